// Round 1
// baseline (82.488 us; speedup 1.0000x reference)
//
#include <hip/hip_runtime.h>
#include <math.h>

#define NATOMS 2000
#define NNBR   30
#define NCONF  8
#define APC    250
#define NRAD   12
#define M3     20
#define H1N    64
#define H2N    32

__device__ __forceinline__ float sigmoidf(float v) {
    return 1.0f / (1.0f + __expf(-v));
}

// one wave (64 threads) per 2 atoms: half = lane>>5 selects atom, row = lane&31 (<30 active)
extern "C" __global__ void __launch_bounds__(64)
fit_main(const float* __restrict__ x, const float* __restrict__ tx,
         const int* __restrict__ uj,
         const float* __restrict__ W1, const float* __restrict__ b1,
         const float* __restrict__ W2, const float* __restrict__ b2,
         const float* __restrict__ W3, const float* __restrict__ b3,
         float* __restrict__ gx, float* __restrict__ e_atom)
{
    const int lane = threadIdx.x;
    const int half = lane >> 5;
    const int row  = lane & 31;
    const int atom = blockIdx.x * 2 + half;
    const bool act = (row < NNBR);

    __shared__ float s_u[2][NNBR][3];
    __shared__ float s_fc[2][NNBR];
    __shared__ float s_d3[2][NNBR][M3 + 1];   // padded to 21 (bank spread)
    __shared__ float s_gd3[2][NNBR][M3 + 1];

    const float k1  = 0.6283185307179586f;   // pi/5
    const float sq  = 0.6324555320336759f;   // sqrt(2/5)
    const float eta = 45.125f;               // 1/(2*dmu^2), dmu=2/19

    float d0 = 0.f, d1 = 0.f, d2 = 0.f;
    float r = 1.f, rinv = 1.f, u0 = 0.f, u1 = 0.f, u2 = 0.f;
    float fc = 0.f, ca = 1.f, sa = 0.f;
    int j = 0;

    if (act) {
        int p = atom * NNBR + row;
        j = uj[p];
        float xi0 = x[atom * 3 + 0], xi1 = x[atom * 3 + 1], xi2 = x[atom * 3 + 2];
        d0 = xi0 - x[j * 3 + 0] - tx[p * 3 + 0];
        d1 = xi1 - x[j * 3 + 1] - tx[p * 3 + 1];
        d2 = xi2 - x[j * 3 + 2] - tx[p * 3 + 2];
        r = sqrtf(d0 * d0 + d1 * d1 + d2 * d2);
        rinv = 1.0f / r;
        u0 = d0 * rinv; u1 = d1 * rinv; u2 = d2 * rinv;
        float a = k1 * r;
        __sincosf(a, &sa, &ca);
        fc = 0.5f * (ca + 1.0f);
        s_u[half][row][0] = u0; s_u[half][row][1] = u1; s_u[half][row][2] = u2;
        s_fc[half][row] = fc;
    }
    __syncthreads();

    // ---------------- 3-body forward: d3[m] = sum_{q!=row} fc_q * exp(-eta*(cos-mu_m)^2)
    float d3r[M3];
#pragma unroll
    for (int m = 0; m < M3; m++) d3r[m] = 0.f;

    if (act) {
        for (int q = 0; q < NNBR; q++) {
            float vq0 = s_u[half][q][0], vq1 = s_u[half][q][1], vq2 = s_u[half][q][2];
            float fq = (q == row) ? 0.f : s_fc[half][q];
            float cs = u0 * vq0 + u1 * vq1 + u2 * vq2;
#pragma unroll
            for (int m = 0; m < M3; m++) {
                float mu = -1.0f + (float)m * (2.0f / 19.0f);
                float t = cs - mu;
                float e = __expf(-eta * t * t);
                d3r[m] = fmaf(fq, e, d3r[m]);
            }
        }
#pragma unroll
        for (int m = 0; m < M3; m++) s_d3[half][row][m] = d3r[m];
    }

    // ---------------- MLP forward: z1 (h-loop unrolled so h1v stays in VGPRs)
    float h1v[H1N];
#pragma unroll
    for (int h = 0; h < H1N; h++) h1v[h] = b1[h];

    if (act) {
        // rbf part via sin recurrence: s_n = sin(n*a)
        float sprev = 0.f, scur = sa;
        float coef = fc * sq * rinv;
        for (int d = 0; d < NRAD; d++) {
            float rb = coef * scur;
            const float* wrow = &W1[d * H1N];
#pragma unroll
            for (int h = 0; h < H1N; h++) h1v[h] = fmaf(rb, wrow[h], h1v[h]);
            float snext = 2.f * ca * scur - sprev;
            sprev = scur; scur = snext;
        }
        for (int d = NRAD; d < NRAD + M3; d++) {
            float dv = s_d3[half][row][d - NRAD];
            const float* wrow = &W1[d * H1N];
#pragma unroll
            for (int h = 0; h < H1N; h++) h1v[h] = fmaf(dv, wrow[h], h1v[h]);
        }
#pragma unroll
        for (int h = 0; h < H1N; h++) h1v[h] = sigmoidf(h1v[h]);
    }

    // ---------------- layer2 fwd + out + backward to g_h1, in one k pass
    float gh1[H1N];
#pragma unroll
    for (int h = 0; h < H1N; h++) gh1[h] = 0.f;
    float out = b3[0];

    if (act) {
        for (int k = 0; k < H2N; k++) {
            float acc = b2[k];
#pragma unroll
            for (int h = 0; h < H1N; h++) acc = fmaf(h1v[h], W2[h * H2N + k], acc);
            float s = sigmoidf(acc);
            float w3 = W3[k];
            out = fmaf(s, w3, out);
            float gz2 = fc * w3 * s * (1.f - s);   // dE/dz2_k  (dE/dout = fc)
#pragma unroll
            for (int h = 0; h < H1N; h++) gh1[h] = fmaf(gz2, W2[h * H2N + k], gh1[h]);
        }
    }
    float eij = act ? out * fc : 0.f;

    // g_z1 = g_h1 * sig'
#pragma unroll
    for (int h = 0; h < H1N; h++) {
        float hv = h1v[h];
        gh1[h] = gh1[h] * hv * (1.f - hv);
    }

    float g_r = 0.f;
    float g_fc = out;   // from eij = out * fc

    if (act) {
        // rbf backward (d=0..11), sin/cos recurrences
        float sprev = 0.f, scur = sa, cprev = 1.f, ccur = ca;
        for (int d = 0; d < NRAD; d++) {
            float gd = 0.f;
            const float* wrow = &W1[d * H1N];
#pragma unroll
            for (int h = 0; h < H1N; h++) gd = fmaf(gh1[h], wrow[h], gd);
            float n = (float)(d + 1);
            g_r  += gd * fc * sq * rinv * (n * k1 * ccur - scur * rinv);
            g_fc += gd * sq * scur * rinv;
            float snext = 2.f * ca * scur - sprev; sprev = scur; scur = snext;
            float cnext = 2.f * ca * ccur - cprev; cprev = ccur; ccur = cnext;
        }
        // g_d3 rows to LDS (cross-row coupling in 3-body backward)
        for (int d = NRAD; d < NRAD + M3; d++) {
            float gd = 0.f;
            const float* wrow = &W1[d * H1N];
#pragma unroll
            for (int h = 0; h < H1N; h++) gd = fmaf(gh1[h], wrow[h], gd);
            s_gd3[half][row][d - NRAD] = gd;
        }
    }
    __syncthreads();

    // ---------------- 3-body backward
    float gu0 = 0.f, gu1 = 0.f, gu2 = 0.f;
    if (act) {
        float A[M3];
#pragma unroll
        for (int m = 0; m < M3; m++) A[m] = s_gd3[half][row][m];
        for (int q = 0; q < NNBR; q++) {
            float vq0 = s_u[half][q][0], vq1 = s_u[half][q][1], vq2 = s_u[half][q][2];
            float fq = s_fc[half][q];
            float cs = u0 * vq0 + u1 * vq1 + u2 * vq2;
            float sA = 0.f, sB = 0.f, sBg = 0.f;
#pragma unroll
            for (int m = 0; m < M3; m++) {
                float mu = -1.0f + (float)m * (2.0f / 19.0f);
                float t = cs - mu;
                float e = __expf(-eta * t * t);
                float de = -2.f * eta * t * e;
                float Bm = s_gd3[half][q][m];
                sA  = fmaf(A[m], de, sA);
                sB  = fmaf(Bm, de, sB);
                sBg = fmaf(Bm, e, sBg);
            }
            if (q != row) {
                g_fc += sBg;                       // fc_row used as weight in row q's d3
                float gcos = fq * sA + fc * sB;    // both orderings of cos(p,q)
                gu0 = fmaf(gcos, vq0, gu0);
                gu1 = fmaf(gcos, vq1, gu1);
                gu2 = fmaf(gcos, vq2, gu2);
            }
        }
    }

    // ---------------- geometry backward + scatter
    float gd0 = 0.f, gd1 = 0.f, gd2 = 0.f;
    if (act) {
        g_r += g_fc * (-0.5f * k1 * sa);          // dfc/dr
        float gdot = gu0 * u0 + gu1 * u1 + gu2 * u2;
        gd0 = g_r * u0 + (gu0 - gdot * u0) * rinv;
        gd1 = g_r * u1 + (gu1 - gdot * u1) * rinv;
        gd2 = g_r * u2 + (gu2 - gdot * u2) * rinv;
        atomicAdd(&gx[j * 3 + 0], -gd0);
        atomicAdd(&gx[j * 3 + 1], -gd1);
        atomicAdd(&gx[j * 3 + 2], -gd2);
    }

    // reduce gd + eij over the 32-lane half (inactive lanes hold zeros)
#pragma unroll
    for (int off = 16; off > 0; off >>= 1) {
        gd0 += __shfl_xor(gd0, off, 32);
        gd1 += __shfl_xor(gd1, off, 32);
        gd2 += __shfl_xor(gd2, off, 32);
        eij += __shfl_xor(eij, off, 32);
    }
    if (row == 0) {
        atomicAdd(&gx[atom * 3 + 0], gd0);
        atomicAdd(&gx[atom * 3 + 1], gd1);
        atomicAdd(&gx[atom * 3 + 2], gd2);
        e_atom[atom] = eij;
    }
}

// blocks 0..7: per-config energy reduction; blocks 8..: forces = -gx
extern "C" __global__ void __launch_bounds__(256)
fit_finalize(const float* __restrict__ e_atom, const float* __restrict__ gx,
             float* __restrict__ out)
{
    int b = blockIdx.x;
    if (b < NCONF) {
        __shared__ float red[256];
        int t = threadIdx.x;
        red[t] = (t < APC) ? e_atom[b * APC + t] : 0.f;
        __syncthreads();
        for (int s = 128; s > 0; s >>= 1) {
            if (t < s) red[t] += red[t + s];
            __syncthreads();
        }
        if (t == 0) out[b] = red[0];
    } else {
        int idx = (b - NCONF) * 256 + threadIdx.x;
        if (idx < NATOMS * 3) out[NCONF + idx] = -gx[idx];
    }
}

extern "C" void kernel_launch(void* const* d_in, const int* in_sizes, int n_in,
                              void* d_out, int out_size, void* d_ws, size_t ws_size,
                              hipStream_t stream)
{
    const float* x  = (const float*)d_in[0];
    const float* tx = (const float*)d_in[1];
    // d_in[2] neighlist, d_in[3] indices, d_in[4] atoms_per_structure, d_in[5] types: derivable
    const int*   uj = (const int*)d_in[7];
    const float* W1 = (const float*)d_in[8];
    const float* b1 = (const float*)d_in[9];
    const float* W2 = (const float*)d_in[10];
    const float* b2 = (const float*)d_in[11];
    const float* W3 = (const float*)d_in[12];
    const float* b3 = (const float*)d_in[13];

    float* gx     = (float*)d_ws;           // [NATOMS*3] accumulated dE/dx
    float* e_atom = gx + NATOMS * 3;        // [NATOMS]   per-atom energy

    hipMemsetAsync(gx, 0, NATOMS * 3 * sizeof(float), stream);

    fit_main<<<NATOMS / 2, 64, 0, stream>>>(x, tx, uj, W1, b1, W2, b2, W3, b3,
                                            gx, e_atom);

    int fblocks = NCONF + (NATOMS * 3 + 255) / 256;   // 8 + 24
    fit_finalize<<<fblocks, 256, 0, stream>>>(e_atom, gx, (float*)d_out);
}

// Round 2
// 64.199 us; speedup vs baseline: 1.2849x; 1.2849x over previous
//
#include <hip/hip_runtime.h>
#include <math.h>

#define NATOMS 2000
#define NNBR   30
#define NCONF  8
#define APC    250
#define NRAD   12
#define M3     20
#define H1N    64
#define H2N    32

__device__ __forceinline__ float sigmoidf(float v) {
    return 1.0f / (1.0f + __expf(-v));
}

// one wave (64 threads) per atom.
// row = lane&31 : neighbor index (30 active)
// half = lane>>5: splits q-loop (15 each) and MLP h-dim (32 each)
extern "C" __global__ void __launch_bounds__(64)
fit_main(const float* __restrict__ x, const float* __restrict__ tx,
         const int* __restrict__ uj,
         const float* __restrict__ W1, const float* __restrict__ b1,
         const float* __restrict__ W2, const float* __restrict__ b2,
         const float* __restrict__ W3, const float* __restrict__ b3,
         float* __restrict__ gx, float* __restrict__ e_atom)
{
    const int lane = threadIdx.x;
    const int row  = lane & 31;
    const int half = lane >> 5;
    const int atom = blockIdx.x;
    const bool act = (row < NNBR);
    const int hbase = half * 32;
    const int q0 = half * 15;

    __shared__ float s_u[NNBR][3];
    __shared__ float s_fc[NNBR];
    __shared__ float s_gd3[NNBR][24];           // 16B-aligned rows
    __shared__ float lW1[NRAD + M3][H1N];       // [32][64]
    __shared__ float lW2t[H2N][H1N + 4];        // transposed, padded rows (272B)

    const float k1  = 0.6283185307179586f;   // pi/5
    const float sq  = 0.6324555320336759f;   // sqrt(2/5)
    const float eta = 45.125f;               // 1/(2*dmu^2), dmu=2/19

    // ---- stage weights into LDS (once per block) ----
    {
        const float4* src = (const float4*)W1;
        float4* dst = (float4*)&lW1[0][0];
#pragma unroll
        for (int t = 0; t < 8; t++) dst[lane + 64 * t] = src[lane + 64 * t];
#pragma unroll
        for (int t = 0; t < 32; t++) {
            int idx = lane + 64 * t;             // 0..2047 over W2 [64][32]
            int h = idx >> 5, k = idx & 31;
            lW2t[k][h] = W2[idx];
        }
    }

    // ---- pair geometry (both halves redundantly) ----
    float r = 1.f, rinv = 1.f, u0 = 0.f, u1 = 0.f, u2 = 0.f;
    float fc = 0.f, ca = 1.f, sa = 0.f;
    int j = 0;
    if (act) {
        int p = atom * NNBR + row;
        j = uj[p];
        float d0 = x[atom * 3 + 0] - x[j * 3 + 0] - tx[p * 3 + 0];
        float d1 = x[atom * 3 + 1] - x[j * 3 + 1] - tx[p * 3 + 1];
        float d2 = x[atom * 3 + 2] - x[j * 3 + 2] - tx[p * 3 + 2];
        r = sqrtf(d0 * d0 + d1 * d1 + d2 * d2);
        rinv = 1.0f / r;
        u0 = d0 * rinv; u1 = d1 * rinv; u2 = d2 * rinv;
        __sincosf(k1 * r, &sa, &ca);
        fc = 0.5f * (ca + 1.0f);
        if (half == 0) {
            s_u[row][0] = u0; s_u[row][1] = u1; s_u[row][2] = u2;
            s_fc[row] = fc;
        }
    } else {
        __sincosf(k1, &sa, &ca);  // keep sa/ca finite for recurrences
    }
    __syncthreads();

    // ---- 3-body forward, q split across halves ----
    float d3p[M3];
#pragma unroll
    for (int m = 0; m < M3; m++) d3p[m] = 0.f;
    if (act) {
        for (int qq = 0; qq < 15; qq++) {
            int q = q0 + qq;
            float vq0 = s_u[q][0], vq1 = s_u[q][1], vq2 = s_u[q][2];
            float fq = (q == row) ? 0.f : s_fc[q];
            float cs = u0 * vq0 + u1 * vq1 + u2 * vq2;
#pragma unroll
            for (int m = 0; m < M3; m++) {
                float mu = -1.0f + (float)m * (2.0f / 19.0f);
                float t = cs - mu;
                d3p[m] = fmaf(fq, __expf(-eta * t * t), d3p[m]);
            }
        }
    }
    float d3f[M3];
#pragma unroll
    for (int m = 0; m < M3; m++) d3f[m] = d3p[m] + __shfl_xor(d3p[m], 32);

    // ---- layer1 forward: z1[h] for h in [hbase, hbase+32) ----
    float h1v[32];
    {
        const float4* bb = (const float4*)&b1[hbase];
#pragma unroll
        for (int t = 0; t < 8; t++) {
            float4 v = bb[t];
            h1v[4 * t + 0] = v.x; h1v[4 * t + 1] = v.y;
            h1v[4 * t + 2] = v.z; h1v[4 * t + 3] = v.w;
        }
    }
    {
        float sprev = 0.f, scur = sa;
        float coef = fc * sq * rinv;
        for (int d = 0; d < NRAD; d++) {
            float rb = coef * scur;
#pragma unroll
            for (int t = 0; t < 8; t++) {
                float4 w = *(const float4*)&lW1[d][hbase + 4 * t];
                h1v[4 * t + 0] = fmaf(rb, w.x, h1v[4 * t + 0]);
                h1v[4 * t + 1] = fmaf(rb, w.y, h1v[4 * t + 1]);
                h1v[4 * t + 2] = fmaf(rb, w.z, h1v[4 * t + 2]);
                h1v[4 * t + 3] = fmaf(rb, w.w, h1v[4 * t + 3]);
            }
            float snext = 2.f * ca * scur - sprev; sprev = scur; scur = snext;
        }
#pragma unroll
        for (int m = 0; m < M3; m++) {
            float dv = d3f[m];
#pragma unroll
            for (int t = 0; t < 8; t++) {
                float4 w = *(const float4*)&lW1[NRAD + m][hbase + 4 * t];
                h1v[4 * t + 0] = fmaf(dv, w.x, h1v[4 * t + 0]);
                h1v[4 * t + 1] = fmaf(dv, w.y, h1v[4 * t + 1]);
                h1v[4 * t + 2] = fmaf(dv, w.z, h1v[4 * t + 2]);
                h1v[4 * t + 3] = fmaf(dv, w.w, h1v[4 * t + 3]);
            }
        }
#pragma unroll
        for (int hh = 0; hh < 32; hh++) h1v[hh] = sigmoidf(h1v[hh]);
    }

    // ---- layer2 fwd + out + backward to g_h1 ----
    float gh1[32];
#pragma unroll
    for (int hh = 0; hh < 32; hh++) gh1[hh] = 0.f;
    float out = b3[0];
    for (int k = 0; k < H2N; k++) {
        float4 wv[8];
#pragma unroll
        for (int t = 0; t < 8; t++) wv[t] = *(const float4*)&lW2t[k][hbase + 4 * t];
        float a0 = 0.f, a1 = 0.f, a2 = 0.f, a3 = 0.f;
#pragma unroll
        for (int t = 0; t < 8; t++) {
            a0 = fmaf(h1v[4 * t + 0], wv[t].x, a0);
            a1 = fmaf(h1v[4 * t + 1], wv[t].y, a1);
            a2 = fmaf(h1v[4 * t + 2], wv[t].z, a2);
            a3 = fmaf(h1v[4 * t + 3], wv[t].w, a3);
        }
        float accp = (a0 + a1) + (a2 + a3);
        float acc = b2[k] + accp + __shfl_xor(accp, 32);
        float s = sigmoidf(acc);
        float w3 = W3[k];
        out = fmaf(s, w3, out);
        float gz2 = fc * w3 * s * (1.f - s);
#pragma unroll
        for (int t = 0; t < 8; t++) {
            gh1[4 * t + 0] = fmaf(gz2, wv[t].x, gh1[4 * t + 0]);
            gh1[4 * t + 1] = fmaf(gz2, wv[t].y, gh1[4 * t + 1]);
            gh1[4 * t + 2] = fmaf(gz2, wv[t].z, gh1[4 * t + 2]);
            gh1[4 * t + 3] = fmaf(gz2, wv[t].w, gh1[4 * t + 3]);
        }
    }
    float eijv = out * fc;

    // g_z1 = g_h1 * sig'
#pragma unroll
    for (int hh = 0; hh < 32; hh++) {
        float hv = h1v[hh];
        gh1[hh] = gh1[hh] * hv * (1.f - hv);
    }

    // ---- layer1 backward: gd per descriptor (shfl-combined across halves) ----
    float g_r = 0.f, g_fcc = out;
    {
        float sprev = 0.f, scur = sa, cprev = 1.f, ccur = ca;
        for (int d = 0; d < NRAD; d++) {
            float a0 = 0.f, a1 = 0.f, a2 = 0.f, a3 = 0.f;
#pragma unroll
            for (int t = 0; t < 8; t++) {
                float4 w = *(const float4*)&lW1[d][hbase + 4 * t];
                a0 = fmaf(gh1[4 * t + 0], w.x, a0);
                a1 = fmaf(gh1[4 * t + 1], w.y, a1);
                a2 = fmaf(gh1[4 * t + 2], w.z, a2);
                a3 = fmaf(gh1[4 * t + 3], w.w, a3);
            }
            float gdp = (a0 + a1) + (a2 + a3);
            float gd = gdp + __shfl_xor(gdp, 32);
            float n = (float)(d + 1);
            g_r  += gd * fc * sq * rinv * (n * k1 * ccur - scur * rinv);
            g_fcc += gd * sq * scur * rinv;
            float snext = 2.f * ca * scur - sprev; sprev = scur; scur = snext;
            float cnext = 2.f * ca * ccur - cprev; cprev = ccur; ccur = cnext;
        }
    }
    float A[M3];
#pragma unroll
    for (int m = 0; m < M3; m++) {
        float a0 = 0.f, a1 = 0.f, a2 = 0.f, a3 = 0.f;
#pragma unroll
        for (int t = 0; t < 8; t++) {
            float4 w = *(const float4*)&lW1[NRAD + m][hbase + 4 * t];
            a0 = fmaf(gh1[4 * t + 0], w.x, a0);
            a1 = fmaf(gh1[4 * t + 1], w.y, a1);
            a2 = fmaf(gh1[4 * t + 2], w.z, a2);
            a3 = fmaf(gh1[4 * t + 3], w.w, a3);
        }
        float gdp = (a0 + a1) + (a2 + a3);
        float gd = gdp + __shfl_xor(gdp, 32);
        A[m] = gd;
        if (act && half == 0) s_gd3[row][m] = gd;
    }
    __syncthreads();

    // ---- 3-body backward, q split across halves ----
    float gu0 = 0.f, gu1 = 0.f, gu2 = 0.f, g_fcp = 0.f;
    if (act) {
        for (int qq = 0; qq < 15; qq++) {
            int q = q0 + qq;
            float vq0 = s_u[q][0], vq1 = s_u[q][1], vq2 = s_u[q][2];
            float fq = s_fc[q];
            float cs = u0 * vq0 + u1 * vq1 + u2 * vq2;
            float sA0 = 0.f, sA1 = 0.f, sB0 = 0.f, sB1 = 0.f, sG0 = 0.f, sG1 = 0.f;
#pragma unroll
            for (int m = 0; m < M3; m += 2) {
                float mu0 = -1.0f + (float)m * (2.0f / 19.0f);
                float mu1 = -1.0f + (float)(m + 1) * (2.0f / 19.0f);
                float t0 = cs - mu0, t1 = cs - mu1;
                float e0 = __expf(-eta * t0 * t0);
                float e1 = __expf(-eta * t1 * t1);
                float de0 = -2.f * eta * t0 * e0;
                float de1 = -2.f * eta * t1 * e1;
                float B0 = s_gd3[q][m], B1 = s_gd3[q][m + 1];
                sA0 = fmaf(A[m], de0, sA0);     sA1 = fmaf(A[m + 1], de1, sA1);
                sB0 = fmaf(B0, de0, sB0);       sB1 = fmaf(B1, de1, sB1);
                sG0 = fmaf(B0, e0, sG0);        sG1 = fmaf(B1, e1, sG1);
            }
            if (q != row) {
                g_fcp += sG0 + sG1;
                float gcos = fq * (sA0 + sA1) + fc * (sB0 + sB1);
                gu0 = fmaf(gcos, vq0, gu0);
                gu1 = fmaf(gcos, vq1, gu1);
                gu2 = fmaf(gcos, vq2, gu2);
            }
        }
    }
    gu0 += __shfl_xor(gu0, 32);
    gu1 += __shfl_xor(gu1, 32);
    gu2 += __shfl_xor(gu2, 32);
    float g_fc = g_fcc + g_fcp + __shfl_xor(g_fcp, 32);

    // ---- geometry backward + scatter (half 0 only) ----
    float gd0 = 0.f, gd1 = 0.f, gd2 = 0.f, eij = 0.f;
    if (act && half == 0) {
        float g_rf = g_r + g_fc * (-0.5f * k1 * sa);
        float gdot = gu0 * u0 + gu1 * u1 + gu2 * u2;
        gd0 = g_rf * u0 + (gu0 - gdot * u0) * rinv;
        gd1 = g_rf * u1 + (gu1 - gdot * u1) * rinv;
        gd2 = g_rf * u2 + (gu2 - gdot * u2) * rinv;
        atomicAdd(&gx[j * 3 + 0], -gd0);
        atomicAdd(&gx[j * 3 + 1], -gd1);
        atomicAdd(&gx[j * 3 + 2], -gd2);
        eij = eijv;
    }
#pragma unroll
    for (int off = 16; off > 0; off >>= 1) {
        gd0 += __shfl_xor(gd0, off);
        gd1 += __shfl_xor(gd1, off);
        gd2 += __shfl_xor(gd2, off);
        eij += __shfl_xor(eij, off);
    }
    if (lane == 0) {
        atomicAdd(&gx[atom * 3 + 0], gd0);
        atomicAdd(&gx[atom * 3 + 1], gd1);
        atomicAdd(&gx[atom * 3 + 2], gd2);
        e_atom[atom] = eij;
    }
}

// blocks 0..7: per-config energy reduction; blocks 8..: forces = -gx
extern "C" __global__ void __launch_bounds__(256)
fit_finalize(const float* __restrict__ e_atom, const float* __restrict__ gx,
             float* __restrict__ out)
{
    int b = blockIdx.x;
    if (b < NCONF) {
        __shared__ float red[256];
        int t = threadIdx.x;
        red[t] = (t < APC) ? e_atom[b * APC + t] : 0.f;
        __syncthreads();
        for (int s = 128; s > 0; s >>= 1) {
            if (t < s) red[t] += red[t + s];
            __syncthreads();
        }
        if (t == 0) out[b] = red[0];
    } else {
        int idx = (b - NCONF) * 256 + threadIdx.x;
        if (idx < NATOMS * 3) out[NCONF + idx] = -gx[idx];
    }
}

extern "C" void kernel_launch(void* const* d_in, const int* in_sizes, int n_in,
                              void* d_out, int out_size, void* d_ws, size_t ws_size,
                              hipStream_t stream)
{
    const float* x  = (const float*)d_in[0];
    const float* tx = (const float*)d_in[1];
    const int*   uj = (const int*)d_in[7];
    const float* W1 = (const float*)d_in[8];
    const float* b1 = (const float*)d_in[9];
    const float* W2 = (const float*)d_in[10];
    const float* b2 = (const float*)d_in[11];
    const float* W3 = (const float*)d_in[12];
    const float* b3 = (const float*)d_in[13];

    float* gx     = (float*)d_ws;           // [NATOMS*3]
    float* e_atom = gx + NATOMS * 3;        // [NATOMS]

    hipMemsetAsync(gx, 0, NATOMS * 3 * sizeof(float), stream);

    fit_main<<<NATOMS, 64, 0, stream>>>(x, tx, uj, W1, b1, W2, b2, W3, b3,
                                        gx, e_atom);

    int fblocks = NCONF + (NATOMS * 3 + 255) / 256;   // 8 + 24
    fit_finalize<<<fblocks, 256, 0, stream>>>(e_atom, gx, (float*)d_out);
}